// Round 10
// baseline (237.780 us; speedup 1.0000x reference)
//
#include <hip/hip_runtime.h>
#include <hip/hip_fp16.h>
#include <math.h>

#define N_NODES 100000
#define N_EDGES 1600000
#define LN_EPS 1e-5f
#define NORM_EPS 1e-12f
#define ROWS_PER_BLOCK 32
#define GEMM_BLOCKS (N_NODES / ROWS_PER_BLOCK)            // 3125, exact
#define WSTRIDE 66   // even (b64-aligned) and 2c+k -> 2-way banks (free)
// R12/R13 ERRATA (measured): scattered partial-line stores pay a full 64B
// fetch+WB PER TOUCH whenever consecutive records of a line are written by
// different workgroups.  Invariant: coalescing happens ONLY when one block
// (one CU/L2) owns all writes to a line.  R14 (WIN 317->292): bucketed
// counting sort.  R15 (WIN 292->254): bucket-level histogram replaced the
// 1.6M random node atomics (+49.4MB WRITE / ~50us in gemm).
// R16 ERRATA (FAILED 254->783): fusing gather into k_place serialized on
// ONE h16 load in flight per wave.  Gather needs unrolled many-loads-in-
// flight, barrier-free waves.  REVERTED.
// R17 (WIN 254->235): flat streams + 32-bit indices, gather 77->65us.
// R18 (neutral 235->232): half2 packing -- VALU cost was addr math.
// R19 (WIN 232->226): wave-uniform addressing (readfirstlane(i) -> s_load
// dst/row_ptr, saddr loads); gather 61->55us, SGPR 32->64 confirms.
// R20: non-gather time has been flat ~170us across R5-R9 -- the serialized
// hist->bscan->gemm->bin->place chain.  gemm is INDEPENDENT of hist/bin;
// both are under-utilized (gemm VALU 24%/HBM 13%; bin latency-bound).
// Merge bin+gemm into ONE dispatch via blockIdx partition (bin blocks
// first; 256-thr uniform; dynamic-LDS union).  Chain: hist -> bscan ->
// [bin||gemm] -> place -> gather.
#define WB 64                                   // nodes per place-bucket
#define NBKT ((N_NODES + WB - 1) / WB)          // 1563
#define BIN_TILE 8192                           // k_hist: 1024 thr x 8 edges
#define BIN_BLOCKS ((N_EDGES + BIN_TILE - 1) / BIN_TILE)  // 196
#define BIN2_TILE 2048                          // fused bin: 256 thr x 8
#define BIN2_BLOCKS ((N_EDGES + BIN2_TILE - 1) / BIN2_TILE)  // 782
#define GB_LDS 25088                            // max(gemm 25088, bin 12504)

// ---------------------------------------------------------------------------
// k_gemm_bin: ONE dispatch, two independent block populations.
//   blockIdx < BIN2_BLOCKS: bucket edges by src>>6 (LDS hist rank + ONE
//     global claim per (block,bucket), scatter packed word (src&63)|(dst<<6)).
//   else: h = x @ W^T + b -> fp16 h16 + fp32 attn scores (R5/R6-proven GEMM:
//     k-loop NOT unrolled -- unrolled spills acc[] at any VGPR budget).
// Parts share no data; __syncthreads is uniform within each block.
// ---------------------------------------------------------------------------
__global__ __launch_bounds__(256) void k_gemm_bin(
    const float* __restrict__ x, const float* __restrict__ W,
    const float* __restrict__ b, const float* __restrict__ a,
    __half* __restrict__ h16,
    float* __restrict__ s_src, float* __restrict__ s_dst,
    const int* __restrict__ ei, int* __restrict__ gbin,
    unsigned int* __restrict__ staged)
{
    extern __shared__ char smem[];
    const int tid = threadIdx.x;

    if (blockIdx.x < BIN2_BLOCKS) {
        // ---- bin part (256 thr, 2048-edge tile) ----
        int* hist = (int*)smem;            // [NBKT]
        int* base = hist + NBKT;           // [NBKT]
        for (int bb = tid; bb < NBKT; bb += 256) hist[bb] = 0;
        __syncthreads();

        int s[8], d[8], r[8];
        const int e0 = blockIdx.x * BIN2_TILE;
        #pragma unroll
        for (int j = 0; j < 8; ++j) {
            const int e = e0 + j * 256 + tid;
            if (e < N_EDGES) {
                s[j] = ei[e];
                d[j] = ei[N_EDGES + e];
                r[j] = atomicAdd(&hist[s[j] >> 6], 1);
            }
        }
        __syncthreads();
        for (int bb = tid; bb < NBKT; bb += 256)
            if (hist[bb]) base[bb] = atomicAdd(&gbin[bb], hist[bb]);
        __syncthreads();
        #pragma unroll
        for (int j = 0; j < 8; ++j) {
            const int e = e0 + j * 256 + tid;
            if (e < N_EDGES)
                staged[(size_t)base[s[j] >> 6] + r[j]] =
                    (unsigned int)((s[j] & 63) | (d[j] << 6));
        }
        return;
    }

    // ---- gemm part ----
    float* WL = (float*)smem;                      // [64*WSTRIDE]
    float* xs = WL + 64 * WSTRIDE;                 // [ROWS_PER_BLOCK*64]
    const int lane = tid & 63;
    const int wv   = tid >> 6;

    for (int idx = tid * 4; idx < 64 * 64; idx += 256 * 4) {
        const float4 w = *(const float4*)(W + idx);
        const int c = idx >> 6, k = idx & 63;
        WL[c * WSTRIDE + k + 0] = w.x;
        WL[c * WSTRIDE + k + 1] = w.y;
        WL[c * WSTRIDE + k + 2] = w.z;
        WL[c * WSTRIDE + k + 3] = w.w;
    }
    const int row0 = (blockIdx.x - BIN2_BLOCKS) * ROWS_PER_BLOCK;
    for (int idx = tid * 4; idx < ROWS_PER_BLOCK * 64; idx += 256 * 4)
        *(float4*)(xs + idx) = *(const float4*)(x + (size_t)row0 * 64 + idx);
    __syncthreads();

    const float bias = b[lane];
    float acc[8];
    #pragma unroll
    for (int r = 0; r < 8; ++r) acc[r] = bias;

    const int rbase = wv * 8;
    const float* wrow = WL + lane * WSTRIDE;
    const float* xrow = xs + rbase * 64;
    #pragma unroll 1   // DO NOT unroll: keeps live set small (R5/R6)
    for (int kk = 0; kk < 64; kk += 4) {
        const float2 w01 = *(const float2*)(wrow + kk);
        const float2 w23 = *(const float2*)(wrow + kk + 2);
        #pragma unroll
        for (int r = 0; r < 8; ++r) {
            const float4 xq = *(const float4*)(xrow + r * 64 + kk);
            acc[r] += xq.x * w01.x + xq.y * w01.y + xq.z * w23.x + xq.w * w23.y;
        }
    }

    const float asrc = a[(lane >> 3) * 16 + (lane & 7)];
    const float adst = a[(lane >> 3) * 16 + 8 + (lane & 7)];
    #pragma unroll
    for (int r = 0; r < 8; ++r) {
        const int row = row0 + rbase + r;
        const float v = acc[r];
        h16[(size_t)row * 64 + lane] = __float2half_rn(v);
        float p = v * asrc, q = v * adst;
        p += __shfl_xor(p, 1);  q += __shfl_xor(q, 1);
        p += __shfl_xor(p, 2);  q += __shfl_xor(q, 2);
        p += __shfl_xor(p, 4);  q += __shfl_xor(q, 4);
        if ((lane & 7) == 0) {
            s_src[row * 8 + (lane >> 3)] = p;
            s_dst[row * 8 + (lane >> 3)] = q;
        }
    }
}

// ---------------------------------------------------------------------------
// k_hist: bucket-level (src>>6) histogram.  LDS compresses 8192 edges/block
// into <=1563 sequential global atomics (294K total).
// ---------------------------------------------------------------------------
__global__ __launch_bounds__(1024) void k_hist(
    const int* __restrict__ ei, int* __restrict__ bhist)
{
    __shared__ int hist[NBKT];
    const int tid = threadIdx.x;
    for (int b = tid; b < NBKT; b += 1024) hist[b] = 0;
    __syncthreads();
    const int e0 = blockIdx.x * BIN_TILE;
    #pragma unroll
    for (int j = 0; j < 8; ++j) {
        const int e = e0 + j * 1024 + tid;
        if (e < N_EDGES) atomicAdd(&hist[ei[e] >> 6], 1);
    }
    __syncthreads();
    for (int b = tid; b < NBKT; b += 1024)
        if (hist[b]) atomicAdd(&bhist[b], hist[b]);
}

// ---------------------------------------------------------------------------
// k_bscan: exclusive scan of the 1563 bucket counts -> bucket_base (segment
// bounds for k_place) + gbin (scatter frontiers for the fused bin part).
// ---------------------------------------------------------------------------
__global__ __launch_bounds__(1024) void k_bscan(
    const int* __restrict__ bhist, int* __restrict__ bucket_base,
    int* __restrict__ gbin)
{
    __shared__ int wsum[16];
    const int tid = threadIdx.x, lane = tid & 63, wv = tid >> 6;

    int v = (tid < NBKT) ? bhist[tid] : 0;
    int sc = v;
    #pragma unroll
    for (int off = 1; off < 64; off <<= 1) {
        int t = __shfl_up(sc, off);
        if (lane >= off) sc += t;
    }
    if (lane == 63) wsum[wv] = sc;
    __syncthreads();
    if (tid < 16) {
        int ws = wsum[tid];
        #pragma unroll
        for (int off = 1; off < 16; off <<= 1) {
            int t = __shfl_up(ws, off);
            if (tid >= off) ws += t;
        }
        wsum[tid] = ws;
    }
    __syncthreads();
    const int pref0 = wv ? wsum[wv - 1] : 0;
    const int ex0 = pref0 + sc - v;
    if (tid < NBKT) { bucket_base[tid] = ex0; gbin[tid] = ex0; }
    const int T1 = wsum[15];
    __syncthreads();

    const int i2 = 1024 + tid;
    int v2 = (i2 < NBKT) ? bhist[i2] : 0;
    int sc2 = v2;
    #pragma unroll
    for (int off = 1; off < 64; off <<= 1) {
        int t = __shfl_up(sc2, off);
        if (lane >= off) sc2 += t;
    }
    if (lane == 63) wsum[wv] = sc2;
    __syncthreads();
    if (tid < 16) {
        int ws = wsum[tid];
        #pragma unroll
        for (int off = 1; off < 16; off <<= 1) {
            int t = __shfl_up(ws, off);
            if (tid >= off) ws += t;
        }
        wsum[tid] = ws;
    }
    __syncthreads();
    const int pref1 = wv ? wsum[wv - 1] : 0;
    const int ex1 = T1 + pref1 + sc2 - v2;
    if (i2 < NBKT) { bucket_base[i2] = ex1; gbin[i2] = ex1; }
    if (tid == 0) bucket_base[NBKT] = N_EDGES;
}

// ---------------------------------------------------------------------------
// k_place: block g owns nodes [g*64, g*64+64) and segment
// [bucket_base[g], bucket_base[g+1]).  Pass A: LDS histogram of the 64 node
// degrees + wave-scan -> row_ptr.  Pass B (segment re-read, L2-hot): alpha
// + slot via LDS cursors; writes TWO flat streams (dst_sorted 4B, alpha16
// 16B) -- both windows block-exclusive per the R14 invariant.
// ---------------------------------------------------------------------------
__global__ __launch_bounds__(1024) void k_place(
    const int* __restrict__ bucket_base, const unsigned int* __restrict__ staged,
    const float* __restrict__ s_src, const float* __restrict__ s_dst,
    int* __restrict__ row_ptr, int* __restrict__ dst_sorted,
    __half* __restrict__ alpha16)
{
    __shared__ int cnt[WB];
    __shared__ int cur[WB];
    const int g   = blockIdx.x;
    const int n0  = g * WB;
    const int tid = threadIdx.x;
    if (tid < WB) cnt[tid] = 0;
    __syncthreads();
    const int beg = bucket_base[g];
    const int end = bucket_base[g + 1];

    for (int j = beg + tid; j < end; j += 1024)
        atomicAdd(&cnt[staged[j] & 63u], 1);
    __syncthreads();
    if (tid < WB) {
        const int c = cnt[tid];
        int sc = c;
        #pragma unroll
        for (int off = 1; off < 64; off <<= 1) {
            int t = __shfl_up(sc, off);
            if (tid >= off) sc += t;
        }
        const int rp = beg + sc - c;     // global exclusive prefix
        cur[tid] = rp;
        if (n0 + tid < N_NODES) row_ptr[n0 + tid] = rp;
    }
    if (g == NBKT - 1 && tid == 0) row_ptr[N_NODES] = N_EDGES;
    __syncthreads();

    for (int j = beg + tid; j < end; j += 1024) {
        const unsigned int w = staged[j];
        const int srcl = (int)(w & 63u);
        const int dst  = (int)(w >> 6);

        const float4 a0 = *(const float4*)(s_src + (size_t)(n0 + srcl) * 8);
        const float4 a1 = *(const float4*)(s_src + (size_t)(n0 + srcl) * 8 + 4);
        const float4 b0 = *(const float4*)(s_dst + (size_t)dst * 8);
        const float4 b1 = *(const float4*)(s_dst + (size_t)dst * 8 + 4);
        float sc[8] = {a0.x + b0.x, a0.y + b0.y, a0.z + b0.z, a0.w + b0.w,
                       a1.x + b1.x, a1.y + b1.y, a1.z + b1.z, a1.w + b1.w};
        float m = -1e30f;
        #pragma unroll
        for (int h = 0; h < 8; ++h) {
            sc[h] = (sc[h] >= 0.f) ? sc[h] : 0.2f * sc[h];
            m = fmaxf(m, sc[h]);
        }
        float sum = 0.f;
        #pragma unroll
        for (int h = 0; h < 8; ++h) { sc[h] = __expf(sc[h] - m); sum += sc[h]; }
        const float inv = 1.f / sum;
        unsigned int q[4];
        #pragma unroll
        for (int jj = 0; jj < 4; ++jj) {
            const unsigned short lo = __half_as_ushort(__float2half_rn(sc[2*jj]   * inv));
            const unsigned short hi = __half_as_ushort(__float2half_rn(sc[2*jj+1] * inv));
            q[jj] = (unsigned int)lo | ((unsigned int)hi << 16);
        }

        const int slot = atomicAdd(&cur[srcl], 1);
        dst_sorted[slot] = dst;
        *(uint4*)(alpha16 + (size_t)slot * 8) = make_uint4(q[0], q[1], q[2], q[3]);
    }
}

// ---------------------------------------------------------------------------
// Gather + epilogue (R19): one wave per node, WAVE-UNIFORM addressing.
// readfirstlane(i) -> i/beg/end/e/dst all in SGPRs: row_ptr & dst_sorted
// load via s_load; h16/alpha16 loads are saddr-form (SGPR base + const
// voffset).  8-deep unroll for loads-in-flight.
// ---------------------------------------------------------------------------
__global__ __launch_bounds__(256) void k_gather(
    const int* __restrict__ row_ptr, const int* __restrict__ dst_sorted,
    const __half* __restrict__ alpha16, const __half* __restrict__ h16,
    const float* __restrict__ x, const float* __restrict__ ln_scale,
    const float* __restrict__ ln_bias, float* __restrict__ out)
{
    const int i = __builtin_amdgcn_readfirstlane(
        blockIdx.x * 4 + (threadIdx.x >> 6));   // wave-uniform in SGPR
    if (i >= N_NODES) return;
    const int lane = threadIdx.x & 63;
    const int head = lane >> 3;

    const int beg = row_ptr[i];                  // s_load (uniform)
    const int end = row_ptr[i + 1];
    const float xres = x[(size_t)i * 64 + lane]; // saddr + lane*4

    float acc = 0.f;
    int e = beg;
    for (; e + 7 < end; e += 8) {
        int d[8];
        #pragma unroll
        for (int j = 0; j < 8; ++j) d[j] = dst_sorted[e + j];   // s_load x8
        float al[8];
        #pragma unroll
        for (int j = 0; j < 8; ++j)
            al[j] = __half2float(alpha16[(size_t)(e + j) * 8 + head]); // saddr
        float hv[8];
        #pragma unroll
        for (int j = 0; j < 8; ++j)
            hv[j] = __half2float(h16[(size_t)d[j] * 64 + lane]);       // saddr
        #pragma unroll
        for (int j = 0; j < 8; ++j) acc = fmaf(al[j], hv[j], acc);
    }
    for (; e + 3 < end; e += 4) {
        int d[4];
        #pragma unroll
        for (int j = 0; j < 4; ++j) d[j] = dst_sorted[e + j];
        float al[4];
        #pragma unroll
        for (int j = 0; j < 4; ++j)
            al[j] = __half2float(alpha16[(size_t)(e + j) * 8 + head]);
        float hv[4];
        #pragma unroll
        for (int j = 0; j < 4; ++j)
            hv[j] = __half2float(h16[(size_t)d[j] * 64 + lane]);
        #pragma unroll
        for (int j = 0; j < 4; ++j) acc = fmaf(al[j], hv[j], acc);
    }
    for (; e < end; ++e)
        acc = fmaf(__half2float(alpha16[(size_t)e * 8 + head]),
                   __half2float(h16[(size_t)dst_sorted[e] * 64 + lane]), acc);

    // epilogue: residual + LayerNorm + L2 normalize
    float v = acc + xres;
    float s = v;
    #pragma unroll
    for (int off = 1; off < 64; off <<= 1) s += __shfl_xor(s, off);
    const float mu = s * (1.f / 64.f);
    const float d = v - mu;
    float vs = d * d;
    #pragma unroll
    for (int off = 1; off < 64; off <<= 1) vs += __shfl_xor(vs, off);
    const float var = vs * (1.f / 64.f);
    float y = d * rsqrtf(var + LN_EPS) * ln_scale[lane] + ln_bias[lane];
    float ss = y * y;
    #pragma unroll
    for (int off = 1; off < 64; off <<= 1) ss += __shfl_xor(ss, off);
    const float norm = sqrtf(ss);
    out[(size_t)i * 64 + lane] = y / fmaxf(norm, NORM_EPS);
}

// ---------------------------------------------------------------------------
extern "C" void kernel_launch(void* const* d_in, const int* in_sizes, int n_in,
                              void* d_out, int out_size, void* d_ws, size_t ws_size,
                              hipStream_t stream)
{
    const float* x        = (const float*)d_in[0];
    const int*   ei       = (const int*)d_in[1];
    const float* W        = (const float*)d_in[2];
    const float* b        = (const float*)d_in[3];
    const float* a        = (const float*)d_in[4];
    const float* ln_scale = (const float*)d_in[5];
    const float* ln_bias  = (const float*)d_in[6];
    float* out = (float*)d_out;

    char* ws = (char*)d_ws;
    size_t off = 0;
    auto alloc = [&](size_t bytes) {
        void* p = ws + off;
        off = (off + bytes + 255) & ~(size_t)255;
        return p;
    };
    __half* h16        = (__half*)alloc((size_t)N_NODES * 64 * 2);
    float*  s_src      = (float*) alloc((size_t)N_NODES * 8 * 4);
    float*  s_dst      = (float*) alloc((size_t)N_NODES * 8 * 4);
    int*    bhist      = (int*)   alloc((size_t)NBKT * 4);
    int*    bucket_base= (int*)   alloc((size_t)(NBKT + 1) * 4);
    int*    gbin       = (int*)   alloc((size_t)NBKT * 4);
    int*    row_ptr    = (int*)   alloc((size_t)(N_NODES + 1) * 4);
    unsigned int* staged = (unsigned int*)alloc((size_t)N_EDGES * 4);
    int*    dst_sorted = (int*)   alloc((size_t)N_EDGES * 4);
    __half* alpha16    = (__half*)alloc((size_t)N_EDGES * 8 * 2);

    hipMemsetAsync(bhist, 0, (size_t)NBKT * 4, stream);

    k_hist    <<<BIN_BLOCKS, 1024, 0, stream>>>(ei, bhist);
    k_bscan   <<<1, 1024, 0, stream>>>(bhist, bucket_base, gbin);
    k_gemm_bin<<<BIN2_BLOCKS + GEMM_BLOCKS, 256, GB_LDS, stream>>>(
        x, W, b, a, h16, s_src, s_dst, ei, gbin, staged);
    k_place   <<<NBKT, 1024, 0, stream>>>(bucket_base, staged, s_src, s_dst,
                                          row_ptr, dst_sorted, alpha16);
    k_gather  <<<(N_NODES + 3) / 4, 256, 0, stream>>>(row_ptr, dst_sorted, alpha16,
                                                      h16, x, ln_scale, ln_bias, out);
}

// Round 11
// 214.608 us; speedup vs baseline: 1.1080x; 1.1080x over previous
//
#include <hip/hip_runtime.h>
#include <hip/hip_fp16.h>
#include <math.h>

#define N_NODES 100000
#define N_EDGES 1600000
#define LN_EPS 1e-5f
#define NORM_EPS 1e-12f
#define ROWS_PER_BLOCK 32
#define GEMM_BLOCKS (N_NODES / ROWS_PER_BLOCK)            // 3125, exact
#define WSTRIDE 66   // even (b64-aligned) and 2c+k -> 2-way banks (free)
// R12/R13 ERRATA (measured): scattered partial-line stores pay a full 64B
// fetch+WB PER TOUCH whenever consecutive records of a line are written by
// different workgroups.  Invariant: coalescing happens ONLY when one block
// (one CU/L2) owns all writes to a line.  R14 (WIN 317->292): bucketed
// counting sort.  R15 (WIN 292->254): bucket-level histogram replaced the
// 1.6M random node atomics (+49.4MB WRITE / ~50us in gemm).
// R16 ERRATA (FAILED 254->783): fusing gather into k_place serialized on
// ONE h16 load in flight per wave.  REVERTED.
// R17 (WIN 254->235): flat streams + 32-bit indices, gather 77->65us.
// R18 (neutral 235->232): half2 packing -- VALU cost was addr math.
// R19 (WIN 232->226): wave-uniform addressing (readfirstlane(i) -> s_load
// dst/row_ptr, saddr loads); gather 61->55us.
// R20 ERRATA (FAILED 226->238): gemm||bin fusion with BIN tile 8192->2048
// cut run length 5.2->1.3 edges -> staged writes re-violated the R14
// invariant (+48MB WRITE measured).  The TILE SIZE was the bug, not the
// co-residency.
// R21: fuse again, bin at 256 thr with the FULL 8192 tile via two-pass
// rank (count -> claim -> re-read ei + rank=atomicAdd(&base,1)); ranks
// need only be unique per (block,bucket).  Run length back to ~5.2.
#define WB 64                                   // nodes per place-bucket
#define NBKT ((N_NODES + WB - 1) / WB)          // 1563
#define BIN_TILE 8192                           // 8192-edge tiles (R14-proven)
#define BIN_BLOCKS ((N_EDGES + BIN_TILE - 1) / BIN_TILE)  // 196
#define GB_LDS 25088                            // max(gemm 25088, bin 12504)

// ---------------------------------------------------------------------------
// k_gemm_bin: ONE dispatch, two independent block populations.
//   blockIdx < BIN_BLOCKS: bucket 8192 edges by src>>6, two-pass rank:
//     A) LDS hist count; B) ONE global claim per (block,bucket);
//     C) re-read ei (L2-hot), rank = atomicAdd(&base[b],1), scatter packed
//     word (src&63)|(dst<<6).  Runs ~5.2 edges, one block per run (R14).
//   else: h = x @ W^T + b -> fp16 h16 + fp32 attn scores (R5/R6-proven GEMM:
//     k-loop NOT unrolled -- unrolled spills acc[] at any VGPR budget).
// Parts share no data; __syncthreads is uniform within each block.
// ---------------------------------------------------------------------------
__global__ __launch_bounds__(256) void k_gemm_bin(
    const float* __restrict__ x, const float* __restrict__ W,
    const float* __restrict__ b, const float* __restrict__ a,
    __half* __restrict__ h16,
    float* __restrict__ s_src, float* __restrict__ s_dst,
    const int* __restrict__ ei, int* __restrict__ gbin,
    unsigned int* __restrict__ staged)
{
    extern __shared__ char smem[];
    const int tid = threadIdx.x;

    if (blockIdx.x < BIN_BLOCKS) {
        // ---- bin part (256 thr, 8192-edge tile, two-pass rank) ----
        int* hist = (int*)smem;            // [NBKT]
        int* base = hist + NBKT;           // [NBKT]
        for (int bb = tid; bb < NBKT; bb += 256) hist[bb] = 0;
        __syncthreads();

        const int e0 = blockIdx.x * BIN_TILE;
        #pragma unroll 4
        for (int j = 0; j < 32; ++j) {
            const int e = e0 + j * 256 + tid;
            if (e < N_EDGES) atomicAdd(&hist[ei[e] >> 6], 1);
        }
        __syncthreads();
        for (int bb = tid; bb < NBKT; bb += 256)
            if (hist[bb]) base[bb] = atomicAdd(&gbin[bb], hist[bb]);
        __syncthreads();
        #pragma unroll 4
        for (int j = 0; j < 32; ++j) {
            const int e = e0 + j * 256 + tid;
            if (e < N_EDGES) {
                const int s = ei[e];
                const int d = ei[N_EDGES + e];
                const int idx = atomicAdd(&base[s >> 6], 1);
                staged[(size_t)idx] = (unsigned int)((s & 63) | (d << 6));
            }
        }
        return;
    }

    // ---- gemm part ----
    float* WL = (float*)smem;                      // [64*WSTRIDE]
    float* xs = WL + 64 * WSTRIDE;                 // [ROWS_PER_BLOCK*64]
    const int lane = tid & 63;
    const int wv   = tid >> 6;

    for (int idx = tid * 4; idx < 64 * 64; idx += 256 * 4) {
        const float4 w = *(const float4*)(W + idx);
        const int c = idx >> 6, k = idx & 63;
        WL[c * WSTRIDE + k + 0] = w.x;
        WL[c * WSTRIDE + k + 1] = w.y;
        WL[c * WSTRIDE + k + 2] = w.z;
        WL[c * WSTRIDE + k + 3] = w.w;
    }
    const int row0 = (blockIdx.x - BIN_BLOCKS) * ROWS_PER_BLOCK;
    for (int idx = tid * 4; idx < ROWS_PER_BLOCK * 64; idx += 256 * 4)
        *(float4*)(xs + idx) = *(const float4*)(x + (size_t)row0 * 64 + idx);
    __syncthreads();

    const float bias = b[lane];
    float acc[8];
    #pragma unroll
    for (int r = 0; r < 8; ++r) acc[r] = bias;

    const int rbase = wv * 8;
    const float* wrow = WL + lane * WSTRIDE;
    const float* xrow = xs + rbase * 64;
    #pragma unroll 1   // DO NOT unroll: keeps live set small (R5/R6)
    for (int kk = 0; kk < 64; kk += 4) {
        const float2 w01 = *(const float2*)(wrow + kk);
        const float2 w23 = *(const float2*)(wrow + kk + 2);
        #pragma unroll
        for (int r = 0; r < 8; ++r) {
            const float4 xq = *(const float4*)(xrow + r * 64 + kk);
            acc[r] += xq.x * w01.x + xq.y * w01.y + xq.z * w23.x + xq.w * w23.y;
        }
    }

    const float asrc = a[(lane >> 3) * 16 + (lane & 7)];
    const float adst = a[(lane >> 3) * 16 + 8 + (lane & 7)];
    #pragma unroll
    for (int r = 0; r < 8; ++r) {
        const int row = row0 + rbase + r;
        const float v = acc[r];
        h16[(size_t)row * 64 + lane] = __float2half_rn(v);
        float p = v * asrc, q = v * adst;
        p += __shfl_xor(p, 1);  q += __shfl_xor(q, 1);
        p += __shfl_xor(p, 2);  q += __shfl_xor(q, 2);
        p += __shfl_xor(p, 4);  q += __shfl_xor(q, 4);
        if ((lane & 7) == 0) {
            s_src[row * 8 + (lane >> 3)] = p;
            s_dst[row * 8 + (lane >> 3)] = q;
        }
    }
}

// ---------------------------------------------------------------------------
// k_hist: bucket-level (src>>6) histogram.  LDS compresses 8192 edges/block
// into <=1563 sequential global atomics (294K total).
// ---------------------------------------------------------------------------
__global__ __launch_bounds__(1024) void k_hist(
    const int* __restrict__ ei, int* __restrict__ bhist)
{
    __shared__ int hist[NBKT];
    const int tid = threadIdx.x;
    for (int b = tid; b < NBKT; b += 1024) hist[b] = 0;
    __syncthreads();
    const int e0 = blockIdx.x * BIN_TILE;
    #pragma unroll
    for (int j = 0; j < 8; ++j) {
        const int e = e0 + j * 1024 + tid;
        if (e < N_EDGES) atomicAdd(&hist[ei[e] >> 6], 1);
    }
    __syncthreads();
    for (int b = tid; b < NBKT; b += 1024)
        if (hist[b]) atomicAdd(&bhist[b], hist[b]);
}

// ---------------------------------------------------------------------------
// k_bscan: exclusive scan of the 1563 bucket counts -> bucket_base (segment
// bounds for k_place) + gbin (scatter frontiers for the fused bin part).
// ---------------------------------------------------------------------------
__global__ __launch_bounds__(1024) void k_bscan(
    const int* __restrict__ bhist, int* __restrict__ bucket_base,
    int* __restrict__ gbin)
{
    __shared__ int wsum[16];
    const int tid = threadIdx.x, lane = tid & 63, wv = tid >> 6;

    int v = (tid < NBKT) ? bhist[tid] : 0;
    int sc = v;
    #pragma unroll
    for (int off = 1; off < 64; off <<= 1) {
        int t = __shfl_up(sc, off);
        if (lane >= off) sc += t;
    }
    if (lane == 63) wsum[wv] = sc;
    __syncthreads();
    if (tid < 16) {
        int ws = wsum[tid];
        #pragma unroll
        for (int off = 1; off < 16; off <<= 1) {
            int t = __shfl_up(ws, off);
            if (tid >= off) ws += t;
        }
        wsum[tid] = ws;
    }
    __syncthreads();
    const int pref0 = wv ? wsum[wv - 1] : 0;
    const int ex0 = pref0 + sc - v;
    if (tid < NBKT) { bucket_base[tid] = ex0; gbin[tid] = ex0; }
    const int T1 = wsum[15];
    __syncthreads();

    const int i2 = 1024 + tid;
    int v2 = (i2 < NBKT) ? bhist[i2] : 0;
    int sc2 = v2;
    #pragma unroll
    for (int off = 1; off < 64; off <<= 1) {
        int t = __shfl_up(sc2, off);
        if (lane >= off) sc2 += t;
    }
    if (lane == 63) wsum[wv] = sc2;
    __syncthreads();
    if (tid < 16) {
        int ws = wsum[tid];
        #pragma unroll
        for (int off = 1; off < 16; off <<= 1) {
            int t = __shfl_up(ws, off);
            if (tid >= off) ws += t;
        }
        wsum[tid] = ws;
    }
    __syncthreads();
    const int pref1 = wv ? wsum[wv - 1] : 0;
    const int ex1 = T1 + pref1 + sc2 - v2;
    if (i2 < NBKT) { bucket_base[i2] = ex1; gbin[i2] = ex1; }
    if (tid == 0) bucket_base[NBKT] = N_EDGES;
}

// ---------------------------------------------------------------------------
// k_place: block g owns nodes [g*64, g*64+64) and segment
// [bucket_base[g], bucket_base[g+1]).  Pass A: LDS histogram of the 64 node
// degrees + wave-scan -> row_ptr.  Pass B (segment re-read, L2-hot): alpha
// + slot via LDS cursors; writes TWO flat streams (dst_sorted 4B, alpha16
// 16B) -- both windows block-exclusive per the R14 invariant.
// ---------------------------------------------------------------------------
__global__ __launch_bounds__(1024) void k_place(
    const int* __restrict__ bucket_base, const unsigned int* __restrict__ staged,
    const float* __restrict__ s_src, const float* __restrict__ s_dst,
    int* __restrict__ row_ptr, int* __restrict__ dst_sorted,
    __half* __restrict__ alpha16)
{
    __shared__ int cnt[WB];
    __shared__ int cur[WB];
    const int g   = blockIdx.x;
    const int n0  = g * WB;
    const int tid = threadIdx.x;
    if (tid < WB) cnt[tid] = 0;
    __syncthreads();
    const int beg = bucket_base[g];
    const int end = bucket_base[g + 1];

    for (int j = beg + tid; j < end; j += 1024)
        atomicAdd(&cnt[staged[j] & 63u], 1);
    __syncthreads();
    if (tid < WB) {
        const int c = cnt[tid];
        int sc = c;
        #pragma unroll
        for (int off = 1; off < 64; off <<= 1) {
            int t = __shfl_up(sc, off);
            if (tid >= off) sc += t;
        }
        const int rp = beg + sc - c;     // global exclusive prefix
        cur[tid] = rp;
        if (n0 + tid < N_NODES) row_ptr[n0 + tid] = rp;
    }
    if (g == NBKT - 1 && tid == 0) row_ptr[N_NODES] = N_EDGES;
    __syncthreads();

    for (int j = beg + tid; j < end; j += 1024) {
        const unsigned int w = staged[j];
        const int srcl = (int)(w & 63u);
        const int dst  = (int)(w >> 6);

        const float4 a0 = *(const float4*)(s_src + (size_t)(n0 + srcl) * 8);
        const float4 a1 = *(const float4*)(s_src + (size_t)(n0 + srcl) * 8 + 4);
        const float4 b0 = *(const float4*)(s_dst + (size_t)dst * 8);
        const float4 b1 = *(const float4*)(s_dst + (size_t)dst * 8 + 4);
        float sc[8] = {a0.x + b0.x, a0.y + b0.y, a0.z + b0.z, a0.w + b0.w,
                       a1.x + b1.x, a1.y + b1.y, a1.z + b1.z, a1.w + b1.w};
        float m = -1e30f;
        #pragma unroll
        for (int h = 0; h < 8; ++h) {
            sc[h] = (sc[h] >= 0.f) ? sc[h] : 0.2f * sc[h];
            m = fmaxf(m, sc[h]);
        }
        float sum = 0.f;
        #pragma unroll
        for (int h = 0; h < 8; ++h) { sc[h] = __expf(sc[h] - m); sum += sc[h]; }
        const float inv = 1.f / sum;
        unsigned int q[4];
        #pragma unroll
        for (int jj = 0; jj < 4; ++jj) {
            const unsigned short lo = __half_as_ushort(__float2half_rn(sc[2*jj]   * inv));
            const unsigned short hi = __half_as_ushort(__float2half_rn(sc[2*jj+1] * inv));
            q[jj] = (unsigned int)lo | ((unsigned int)hi << 16);
        }

        const int slot = atomicAdd(&cur[srcl], 1);
        dst_sorted[slot] = dst;
        *(uint4*)(alpha16 + (size_t)slot * 8) = make_uint4(q[0], q[1], q[2], q[3]);
    }
}

// ---------------------------------------------------------------------------
// Gather + epilogue (R19): one wave per node, WAVE-UNIFORM addressing.
// readfirstlane(i) -> i/beg/end/e/dst all in SGPRs: row_ptr & dst_sorted
// load via s_load; h16/alpha16 loads are saddr-form (SGPR base + const
// voffset).  8-deep unroll for loads-in-flight.
// ---------------------------------------------------------------------------
__global__ __launch_bounds__(256) void k_gather(
    const int* __restrict__ row_ptr, const int* __restrict__ dst_sorted,
    const __half* __restrict__ alpha16, const __half* __restrict__ h16,
    const float* __restrict__ x, const float* __restrict__ ln_scale,
    const float* __restrict__ ln_bias, float* __restrict__ out)
{
    const int i = __builtin_amdgcn_readfirstlane(
        blockIdx.x * 4 + (threadIdx.x >> 6));   // wave-uniform in SGPR
    if (i >= N_NODES) return;
    const int lane = threadIdx.x & 63;
    const int head = lane >> 3;

    const int beg = row_ptr[i];                  // s_load (uniform)
    const int end = row_ptr[i + 1];
    const float xres = x[(size_t)i * 64 + lane]; // saddr + lane*4

    float acc = 0.f;
    int e = beg;
    for (; e + 7 < end; e += 8) {
        int d[8];
        #pragma unroll
        for (int j = 0; j < 8; ++j) d[j] = dst_sorted[e + j];   // s_load x8
        float al[8];
        #pragma unroll
        for (int j = 0; j < 8; ++j)
            al[j] = __half2float(alpha16[(size_t)(e + j) * 8 + head]); // saddr
        float hv[8];
        #pragma unroll
        for (int j = 0; j < 8; ++j)
            hv[j] = __half2float(h16[(size_t)d[j] * 64 + lane]);       // saddr
        #pragma unroll
        for (int j = 0; j < 8; ++j) acc = fmaf(al[j], hv[j], acc);
    }
    for (; e + 3 < end; e += 4) {
        int d[4];
        #pragma unroll
        for (int j = 0; j < 4; ++j) d[j] = dst_sorted[e + j];
        float al[4];
        #pragma unroll
        for (int j = 0; j < 4; ++j)
            al[j] = __half2float(alpha16[(size_t)(e + j) * 8 + head]);
        float hv[4];
        #pragma unroll
        for (int j = 0; j < 4; ++j)
            hv[j] = __half2float(h16[(size_t)d[j] * 64 + lane]);
        #pragma unroll
        for (int j = 0; j < 4; ++j) acc = fmaf(al[j], hv[j], acc);
    }
    for (; e < end; ++e)
        acc = fmaf(__half2float(alpha16[(size_t)e * 8 + head]),
                   __half2float(h16[(size_t)dst_sorted[e] * 64 + lane]), acc);

    // epilogue: residual + LayerNorm + L2 normalize
    float v = acc + xres;
    float s = v;
    #pragma unroll
    for (int off = 1; off < 64; off <<= 1) s += __shfl_xor(s, off);
    const float mu = s * (1.f / 64.f);
    const float d = v - mu;
    float vs = d * d;
    #pragma unroll
    for (int off = 1; off < 64; off <<= 1) vs += __shfl_xor(vs, off);
    const float var = vs * (1.f / 64.f);
    float y = d * rsqrtf(var + LN_EPS) * ln_scale[lane] + ln_bias[lane];
    float ss = y * y;
    #pragma unroll
    for (int off = 1; off < 64; off <<= 1) ss += __shfl_xor(ss, off);
    const float norm = sqrtf(ss);
    out[(size_t)i * 64 + lane] = y / fmaxf(norm, NORM_EPS);
}

// ---------------------------------------------------------------------------
extern "C" void kernel_launch(void* const* d_in, const int* in_sizes, int n_in,
                              void* d_out, int out_size, void* d_ws, size_t ws_size,
                              hipStream_t stream)
{
    const float* x        = (const float*)d_in[0];
    const int*   ei       = (const int*)d_in[1];
    const float* W        = (const float*)d_in[2];
    const float* b        = (const float*)d_in[3];
    const float* a        = (const float*)d_in[4];
    const float* ln_scale = (const float*)d_in[5];
    const float* ln_bias  = (const float*)d_in[6];
    float* out = (float*)d_out;

    char* ws = (char*)d_ws;
    size_t off = 0;
    auto alloc = [&](size_t bytes) {
        void* p = ws + off;
        off = (off + bytes + 255) & ~(size_t)255;
        return p;
    };
    __half* h16        = (__half*)alloc((size_t)N_NODES * 64 * 2);
    float*  s_src      = (float*) alloc((size_t)N_NODES * 8 * 4);
    float*  s_dst      = (float*) alloc((size_t)N_NODES * 8 * 4);
    int*    bhist      = (int*)   alloc((size_t)NBKT * 4);
    int*    bucket_base= (int*)   alloc((size_t)(NBKT + 1) * 4);
    int*    gbin       = (int*)   alloc((size_t)NBKT * 4);
    int*    row_ptr    = (int*)   alloc((size_t)(N_NODES + 1) * 4);
    unsigned int* staged = (unsigned int*)alloc((size_t)N_EDGES * 4);
    int*    dst_sorted = (int*)   alloc((size_t)N_EDGES * 4);
    __half* alpha16    = (__half*)alloc((size_t)N_EDGES * 8 * 2);

    hipMemsetAsync(bhist, 0, (size_t)NBKT * 4, stream);

    k_hist    <<<BIN_BLOCKS, 1024, 0, stream>>>(ei, bhist);
    k_bscan   <<<1, 1024, 0, stream>>>(bhist, bucket_base, gbin);
    k_gemm_bin<<<BIN_BLOCKS + GEMM_BLOCKS, 256, GB_LDS, stream>>>(
        x, W, b, a, h16, s_src, s_dst, ei, gbin, staged);
    k_place   <<<NBKT, 1024, 0, stream>>>(bucket_base, staged, s_src, s_dst,
                                          row_ptr, dst_sorted, alpha16);
    k_gather  <<<(N_NODES + 3) / 4, 256, 0, stream>>>(row_ptr, dst_sorted, alpha16,
                                                      h16, x, ln_scale, ln_bias, out);
}

// Round 12
// 200.724 us; speedup vs baseline: 1.1846x; 1.0692x over previous
//
#include <hip/hip_runtime.h>
#include <hip/hip_fp16.h>
#include <math.h>

#define N_NODES 100000
#define N_EDGES 1600000
#define LN_EPS 1e-5f
#define NORM_EPS 1e-12f
#define ROWS_PER_BLOCK 32
#define GEMM_BLOCKS (N_NODES / ROWS_PER_BLOCK)            // 3125, exact
#define WSTRIDE 66   // even (b64-aligned) and 2c+k -> 2-way banks (free)
// R12/R13 ERRATA (measured): scattered partial-line stores pay a full 64B
// fetch+WB PER TOUCH whenever consecutive records of a line are written by
// different workgroups.  Invariant: coalescing happens ONLY when one block
// (one CU/L2) owns all writes to a line.  R14 (WIN 317->292): bucketed
// counting sort.  R15 (WIN 292->254): bucket-level histogram.
// R16 ERRATA (FAILED 254->783): LDS-queue gather fusion serialized on ONE
// h16 load in flight per wave.  Lesson: gather must keep an unrolled
// many-loads-in-flight, barrier-free wave structure.
// R17 (WIN 254->235): flat streams + 32-bit indices.
// R18 (neutral): half2 packing -- VALU cost was addr math.
// R19 (WIN 232->226): wave-uniform addressing (readfirstlane -> s_load /
// saddr); gather 61->55us.
// R20 ERRATA (FAILED): bin tile 2048 cut run length 5.2->1.3 -> R14
// violation (+48MB WRITE).  R21 (WIN 226->215): gemm||bin fusion with FULL
// 8192 tile via two-pass rank; fused 55us vs ~65-70 serialized.
// R22: place+gather are bucket-parallel over the SAME buckets, and place's
// 38.4MB stream write is read right back by gather (32MB of its FETCH).
// Fuse with LDS hand-off (alpha+dst in 26KB LDS, CAP=1280 = mean+8sigma,
// global-overflow fallback); gather phase KEEPS the R19 structure (8-deep
// unrolled h16 loads, readfirstlane scalar addressing) -- the R16 mechanism
// is avoided.  row_ptr deleted entirely.
#define WB 64                                   // nodes per place-bucket
#define NBKT ((N_NODES + WB - 1) / WB)          // 1563
#define BIN_TILE 8192                           // 8192-edge tiles (R14-proven)
#define BIN_BLOCKS ((N_EDGES + BIN_TILE - 1) / BIN_TILE)  // 196
#define GB_LDS 25088                            // max(gemm 25088, bin 12504)
#define CAP 1280     // LDS edges/bucket: mean 1024, sigma~32 -> 8sigma

// ---------------------------------------------------------------------------
// k_gemm_bin: ONE dispatch, two independent block populations (R21-proven).
//   blockIdx < BIN_BLOCKS: bucket 8192 edges by src>>6, two-pass rank:
//     A) LDS hist count; B) ONE global claim per (block,bucket);
//     C) re-read ei (L2-hot), rank = atomicAdd(&base[b],1), scatter packed
//     word (src&63)|(dst<<6).  Runs ~5.2 edges, one block per run (R14).
//   else: h = x @ W^T + b -> fp16 h16 + fp32 attn scores (R5/R6-proven GEMM:
//     k-loop NOT unrolled -- unrolled spills acc[] at any VGPR budget).
// ---------------------------------------------------------------------------
__global__ __launch_bounds__(256) void k_gemm_bin(
    const float* __restrict__ x, const float* __restrict__ W,
    const float* __restrict__ b, const float* __restrict__ a,
    __half* __restrict__ h16,
    float* __restrict__ s_src, float* __restrict__ s_dst,
    const int* __restrict__ ei, int* __restrict__ gbin,
    unsigned int* __restrict__ staged)
{
    extern __shared__ char smem[];
    const int tid = threadIdx.x;

    if (blockIdx.x < BIN_BLOCKS) {
        int* hist = (int*)smem;            // [NBKT]
        int* base = hist + NBKT;           // [NBKT]
        for (int bb = tid; bb < NBKT; bb += 256) hist[bb] = 0;
        __syncthreads();

        const int e0 = blockIdx.x * BIN_TILE;
        #pragma unroll 4
        for (int j = 0; j < 32; ++j) {
            const int e = e0 + j * 256 + tid;
            if (e < N_EDGES) atomicAdd(&hist[ei[e] >> 6], 1);
        }
        __syncthreads();
        for (int bb = tid; bb < NBKT; bb += 256)
            if (hist[bb]) base[bb] = atomicAdd(&gbin[bb], hist[bb]);
        __syncthreads();
        #pragma unroll 4
        for (int j = 0; j < 32; ++j) {
            const int e = e0 + j * 256 + tid;
            if (e < N_EDGES) {
                const int s = ei[e];
                const int d = ei[N_EDGES + e];
                const int idx = atomicAdd(&base[s >> 6], 1);
                staged[(size_t)idx] = (unsigned int)((s & 63) | (d << 6));
            }
        }
        return;
    }

    // ---- gemm part ----
    float* WL = (float*)smem;                      // [64*WSTRIDE]
    float* xs = WL + 64 * WSTRIDE;                 // [ROWS_PER_BLOCK*64]
    const int lane = tid & 63;
    const int wv   = tid >> 6;

    for (int idx = tid * 4; idx < 64 * 64; idx += 256 * 4) {
        const float4 w = *(const float4*)(W + idx);
        const int c = idx >> 6, k = idx & 63;
        WL[c * WSTRIDE + k + 0] = w.x;
        WL[c * WSTRIDE + k + 1] = w.y;
        WL[c * WSTRIDE + k + 2] = w.z;
        WL[c * WSTRIDE + k + 3] = w.w;
    }
    const int row0 = (blockIdx.x - BIN_BLOCKS) * ROWS_PER_BLOCK;
    for (int idx = tid * 4; idx < ROWS_PER_BLOCK * 64; idx += 256 * 4)
        *(float4*)(xs + idx) = *(const float4*)(x + (size_t)row0 * 64 + idx);
    __syncthreads();

    const float bias = b[lane];
    float acc[8];
    #pragma unroll
    for (int r = 0; r < 8; ++r) acc[r] = bias;

    const int rbase = wv * 8;
    const float* wrow = WL + lane * WSTRIDE;
    const float* xrow = xs + rbase * 64;
    #pragma unroll 1   // DO NOT unroll: keeps live set small (R5/R6)
    for (int kk = 0; kk < 64; kk += 4) {
        const float2 w01 = *(const float2*)(wrow + kk);
        const float2 w23 = *(const float2*)(wrow + kk + 2);
        #pragma unroll
        for (int r = 0; r < 8; ++r) {
            const float4 xq = *(const float4*)(xrow + r * 64 + kk);
            acc[r] += xq.x * w01.x + xq.y * w01.y + xq.z * w23.x + xq.w * w23.y;
        }
    }

    const float asrc = a[(lane >> 3) * 16 + (lane & 7)];
    const float adst = a[(lane >> 3) * 16 + 8 + (lane & 7)];
    #pragma unroll
    for (int r = 0; r < 8; ++r) {
        const int row = row0 + rbase + r;
        const float v = acc[r];
        h16[(size_t)row * 64 + lane] = __float2half_rn(v);
        float p = v * asrc, q = v * adst;
        p += __shfl_xor(p, 1);  q += __shfl_xor(q, 1);
        p += __shfl_xor(p, 2);  q += __shfl_xor(q, 2);
        p += __shfl_xor(p, 4);  q += __shfl_xor(q, 4);
        if ((lane & 7) == 0) {
            s_src[row * 8 + (lane >> 3)] = p;
            s_dst[row * 8 + (lane >> 3)] = q;
        }
    }
}

// ---------------------------------------------------------------------------
// k_hist: bucket-level (src>>6) histogram (R15-proven).
// ---------------------------------------------------------------------------
__global__ __launch_bounds__(1024) void k_hist(
    const int* __restrict__ ei, int* __restrict__ bhist)
{
    __shared__ int hist[NBKT];
    const int tid = threadIdx.x;
    for (int b = tid; b < NBKT; b += 1024) hist[b] = 0;
    __syncthreads();
    const int e0 = blockIdx.x * BIN_TILE;
    #pragma unroll
    for (int j = 0; j < 8; ++j) {
        const int e = e0 + j * 1024 + tid;
        if (e < N_EDGES) atomicAdd(&hist[ei[e] >> 6], 1);
    }
    __syncthreads();
    for (int b = tid; b < NBKT; b += 1024)
        if (hist[b]) atomicAdd(&bhist[b], hist[b]);
}

// ---------------------------------------------------------------------------
// k_bscan: exclusive scan of the 1563 bucket counts -> bucket_base (segment
// bounds) + gbin (scatter frontiers for the fused bin part).
// ---------------------------------------------------------------------------
__global__ __launch_bounds__(1024) void k_bscan(
    const int* __restrict__ bhist, int* __restrict__ bucket_base,
    int* __restrict__ gbin)
{
    __shared__ int wsum[16];
    const int tid = threadIdx.x, lane = tid & 63, wv = tid >> 6;

    int v = (tid < NBKT) ? bhist[tid] : 0;
    int sc = v;
    #pragma unroll
    for (int off = 1; off < 64; off <<= 1) {
        int t = __shfl_up(sc, off);
        if (lane >= off) sc += t;
    }
    if (lane == 63) wsum[wv] = sc;
    __syncthreads();
    if (tid < 16) {
        int ws = wsum[tid];
        #pragma unroll
        for (int off = 1; off < 16; off <<= 1) {
            int t = __shfl_up(ws, off);
            if (tid >= off) ws += t;
        }
        wsum[tid] = ws;
    }
    __syncthreads();
    const int pref0 = wv ? wsum[wv - 1] : 0;
    const int ex0 = pref0 + sc - v;
    if (tid < NBKT) { bucket_base[tid] = ex0; gbin[tid] = ex0; }
    const int T1 = wsum[15];
    __syncthreads();

    const int i2 = 1024 + tid;
    int v2 = (i2 < NBKT) ? bhist[i2] : 0;
    int sc2 = v2;
    #pragma unroll
    for (int off = 1; off < 64; off <<= 1) {
        int t = __shfl_up(sc2, off);
        if (lane >= off) sc2 += t;
    }
    if (lane == 63) wsum[wv] = sc2;
    __syncthreads();
    if (tid < 16) {
        int ws = wsum[tid];
        #pragma unroll
        for (int off = 1; off < 16; off <<= 1) {
            int t = __shfl_up(ws, off);
            if (tid >= off) ws += t;
        }
        wsum[tid] = ws;
    }
    __syncthreads();
    const int pref1 = wv ? wsum[wv - 1] : 0;
    const int ex1 = T1 + pref1 + sc2 - v2;
    if (i2 < NBKT) { bucket_base[i2] = ex1; gbin[i2] = ex1; }
    if (tid == 0) bucket_base[NBKT] = N_EDGES;
}

// ---------------------------------------------------------------------------
// k_place_gather (R22): block g owns nodes [g*64, g*64+64) and segment
// [bucket_base[g], bucket_base[g+1]).
//   A) LDS degree histogram + wave-scan -> LOCAL row_ptr (lrow, LDS only).
//   B) per-edge alpha (proven numerics) -> LDS records {uint4 alpha, dst};
//      local slot via LDS cursors.  Overflow past CAP -> global fallback
//      (8-sigma event; correctness only).
//   C) gather with the R19 structure: 16 waves x 4 nodes, 8-deep unrolled
//      h16 loads in flight, readfirstlane(dstl[e]) -> SGPR h16 base,
//      alpha broadcast-read from LDS; LN + L2 epilogue; coalesced out.
// Deletes: 38.4MB stream write + 32MB stream read + row_ptr + 1 dispatch.
// ---------------------------------------------------------------------------
__global__ __launch_bounds__(1024) void k_place_gather(
    const int* __restrict__ bucket_base, const unsigned int* __restrict__ staged,
    const float* __restrict__ s_src, const float* __restrict__ s_dst,
    const __half* __restrict__ h16, const float* __restrict__ x,
    const float* __restrict__ ln_scale, const float* __restrict__ ln_bias,
    int* __restrict__ dst_ovf, __half* __restrict__ alpha_ovf,
    float* __restrict__ out)
{
    __shared__ int lrow[WB + 1];
    __shared__ int cur[WB];
    __shared__ unsigned int dstl[CAP];
    __shared__ uint4 alds[CAP];

    const int g   = blockIdx.x;
    const int n0  = g * WB;
    const int tid = threadIdx.x;
    if (tid < WB) cur[tid] = 0;
    __syncthreads();
    const int beg = bucket_base[g];
    const int end = bucket_base[g + 1];

    // A: degree histogram
    for (int j = beg + tid; j < end; j += 1024)
        atomicAdd(&cur[staged[j] & 63u], 1);
    __syncthreads();
    if (tid < WB) {
        const int c = cur[tid];
        int sc = c;
        #pragma unroll
        for (int off = 1; off < 64; off <<= 1) {
            int t = __shfl_up(sc, off);
            if (tid >= off) sc += t;
        }
        lrow[tid] = sc - c;          // local exclusive prefix
        cur[tid]  = sc - c;          // local cursor
        if (tid == WB - 1) lrow[WB] = sc;
    }
    __syncthreads();

    // B: alpha compute -> LDS records
    for (int j = beg + tid; j < end; j += 1024) {
        const unsigned int w = staged[j];
        const int srcl = (int)(w & 63u);
        const int dst  = (int)(w >> 6);

        const float4 a0 = *(const float4*)(s_src + (size_t)(n0 + srcl) * 8);
        const float4 a1 = *(const float4*)(s_src + (size_t)(n0 + srcl) * 8 + 4);
        const float4 b0 = *(const float4*)(s_dst + (size_t)dst * 8);
        const float4 b1 = *(const float4*)(s_dst + (size_t)dst * 8 + 4);
        float sc[8] = {a0.x + b0.x, a0.y + b0.y, a0.z + b0.z, a0.w + b0.w,
                       a1.x + b1.x, a1.y + b1.y, a1.z + b1.z, a1.w + b1.w};
        float m = -1e30f;
        #pragma unroll
        for (int h = 0; h < 8; ++h) {
            sc[h] = (sc[h] >= 0.f) ? sc[h] : 0.2f * sc[h];
            m = fmaxf(m, sc[h]);
        }
        float sum = 0.f;
        #pragma unroll
        for (int h = 0; h < 8; ++h) { sc[h] = __expf(sc[h] - m); sum += sc[h]; }
        const float inv = 1.f / sum;
        unsigned int q[4];
        #pragma unroll
        for (int jj = 0; jj < 4; ++jj) {
            const unsigned short lo = __half_as_ushort(__float2half_rn(sc[2*jj]   * inv));
            const unsigned short hi = __half_as_ushort(__float2half_rn(sc[2*jj+1] * inv));
            q[jj] = (unsigned int)lo | ((unsigned int)hi << 16);
        }

        const int ls = atomicAdd(&cur[srcl], 1);     // local slot
        if (ls < CAP) {
            dstl[ls] = (unsigned int)dst;
            alds[ls] = make_uint4(q[0], q[1], q[2], q[3]);
        } else {                                      // 8-sigma fallback
            dst_ovf[beg + ls] = dst;
            *(uint4*)(alpha_ovf + (size_t)(beg + ls) * 8) =
                make_uint4(q[0], q[1], q[2], q[3]);
        }
    }
    __syncthreads();

    // C: gather + epilogue (R19 structure)
    const int lane = tid & 63;
    const int wv   = tid >> 6;
    const int head = lane >> 3;

    #pragma unroll 1
    for (int r = 0; r < 4; ++r) {
        const int nl = wv * 4 + r;
        const int i  = n0 + nl;
        if (i >= N_NODES) continue;
        const int bl = lrow[nl];
        const int el = lrow[nl + 1];
        const float xres = x[(size_t)i * 64 + lane];

        float acc = 0.f;
        if (el <= CAP) {
            int e = bl;
            for (; e + 7 < el; e += 8) {
                int d[8];
                #pragma unroll
                for (int j = 0; j < 8; ++j)
                    d[j] = __builtin_amdgcn_readfirstlane((int)dstl[e + j]);
                float al[8];
                #pragma unroll
                for (int j = 0; j < 8; ++j)
                    al[j] = __half2float(((const __half*)&alds[e + j])[head]);
                float hv[8];
                #pragma unroll
                for (int j = 0; j < 8; ++j)
                    hv[j] = __half2float(h16[(size_t)d[j] * 64 + lane]);
                #pragma unroll
                for (int j = 0; j < 8; ++j) acc = fmaf(al[j], hv[j], acc);
            }
            for (; e + 3 < el; e += 4) {
                int d[4];
                #pragma unroll
                for (int j = 0; j < 4; ++j)
                    d[j] = __builtin_amdgcn_readfirstlane((int)dstl[e + j]);
                float al[4];
                #pragma unroll
                for (int j = 0; j < 4; ++j)
                    al[j] = __half2float(((const __half*)&alds[e + j])[head]);
                float hv[4];
                #pragma unroll
                for (int j = 0; j < 4; ++j)
                    hv[j] = __half2float(h16[(size_t)d[j] * 64 + lane]);
                #pragma unroll
                for (int j = 0; j < 4; ++j) acc = fmaf(al[j], hv[j], acc);
            }
            for (; e < el; ++e) {
                const int d = __builtin_amdgcn_readfirstlane((int)dstl[e]);
                acc = fmaf(__half2float(((const __half*)&alds[e])[head]),
                           __half2float(h16[(size_t)d * 64 + lane]), acc);
            }
        } else {
            // rare overflow path (correctness only)
            for (int e = bl; e < el; ++e) {
                int d; float al;
                if (e < CAP) {
                    d  = (int)dstl[e];
                    al = __half2float(((const __half*)&alds[e])[head]);
                } else {
                    d  = dst_ovf[beg + e];
                    al = __half2float(alpha_ovf[(size_t)(beg + e) * 8 + head]);
                }
                acc = fmaf(al, __half2float(h16[(size_t)d * 64 + lane]), acc);
            }
        }

        // epilogue: residual + LayerNorm + L2 normalize
        float v = acc + xres;
        float s = v;
        #pragma unroll
        for (int off = 1; off < 64; off <<= 1) s += __shfl_xor(s, off);
        const float mu = s * (1.f / 64.f);
        const float dd = v - mu;
        float vs = dd * dd;
        #pragma unroll
        for (int off = 1; off < 64; off <<= 1) vs += __shfl_xor(vs, off);
        const float var = vs * (1.f / 64.f);
        float y = dd * rsqrtf(var + LN_EPS) * ln_scale[lane] + ln_bias[lane];
        float ss = y * y;
        #pragma unroll
        for (int off = 1; off < 64; off <<= 1) ss += __shfl_xor(ss, off);
        const float norm = sqrtf(ss);
        out[(size_t)i * 64 + lane] = y / fmaxf(norm, NORM_EPS);
    }
}

// ---------------------------------------------------------------------------
extern "C" void kernel_launch(void* const* d_in, const int* in_sizes, int n_in,
                              void* d_out, int out_size, void* d_ws, size_t ws_size,
                              hipStream_t stream)
{
    const float* x        = (const float*)d_in[0];
    const int*   ei       = (const int*)d_in[1];
    const float* W        = (const float*)d_in[2];
    const float* b        = (const float*)d_in[3];
    const float* a        = (const float*)d_in[4];
    const float* ln_scale = (const float*)d_in[5];
    const float* ln_bias  = (const float*)d_in[6];
    float* out = (float*)d_out;

    char* ws = (char*)d_ws;
    size_t off = 0;
    auto alloc = [&](size_t bytes) {
        void* p = ws + off;
        off = (off + bytes + 255) & ~(size_t)255;
        return p;
    };
    __half* h16        = (__half*)alloc((size_t)N_NODES * 64 * 2);
    float*  s_src      = (float*) alloc((size_t)N_NODES * 8 * 4);
    float*  s_dst      = (float*) alloc((size_t)N_NODES * 8 * 4);
    int*    bhist      = (int*)   alloc((size_t)NBKT * 4);
    int*    bucket_base= (int*)   alloc((size_t)(NBKT + 1) * 4);
    int*    gbin       = (int*)   alloc((size_t)NBKT * 4);
    unsigned int* staged = (unsigned int*)alloc((size_t)N_EDGES * 4);
    int*    dst_ovf    = (int*)   alloc((size_t)N_EDGES * 4);
    __half* alpha_ovf  = (__half*)alloc((size_t)N_EDGES * 8 * 2);

    hipMemsetAsync(bhist, 0, (size_t)NBKT * 4, stream);

    k_hist        <<<BIN_BLOCKS, 1024, 0, stream>>>(ei, bhist);
    k_bscan       <<<1, 1024, 0, stream>>>(bhist, bucket_base, gbin);
    k_gemm_bin    <<<BIN_BLOCKS + GEMM_BLOCKS, 256, GB_LDS, stream>>>(
        x, W, b, a, h16, s_src, s_dst, ei, gbin, staged);
    k_place_gather<<<NBKT, 1024, 0, stream>>>(bucket_base, staged, s_src, s_dst,
                                              h16, x, ln_scale, ln_bias,
                                              dst_ovf, alpha_ovf, out);
}